// Round 7
// baseline (206.892 us; speedup 1.0000x reference)
//
#include <hip/hip_runtime.h>
#include <hip/hip_bf16.h>

typedef __bf16 bf16;
typedef __bf16 bf16x8 __attribute__((ext_vector_type(8)));
typedef __bf16 bf16x4 __attribute__((ext_vector_type(4)));
typedef float  f32x4  __attribute__((ext_vector_type(4)));

#define MFMA16(a,b,c) __builtin_amdgcn_mfma_f32_16x16x32_bf16(a, b, c, 0, 0, 0)

// async global->LDS, 16B per lane; lds dst is wave-uniform base + lane*16
__device__ __forceinline__ void gl2lds16(const bf16* g, bf16* l) {
    __builtin_amdgcn_global_load_lds(
        (__attribute__((address_space(1))) void*)g,
        (__attribute__((address_space(3))) void*)l, 16, 0, 0);
}

// ---------------------------------------------------------------------------
// Fused prep: blocks [0,6144) fp32->bf16 cvt of q|k|v; [6144,6912) Wq/Wk/Wv
// transpose; [6912,7168) Wo transpose.
// ---------------------------------------------------------------------------
__global__ __launch_bounds__(256)
void prep_kernel(const float* __restrict__ q, const float* __restrict__ k,
                 const float* __restrict__ v, const float* __restrict__ Wq,
                 const float* __restrict__ Wk, const float* __restrict__ Wv,
                 const float* __restrict__ Wo, bf16* __restrict__ Xcat,
                 bf16* __restrict__ Wqkv, bf16* __restrict__ Wot)
{
    __shared__ bf16 Tl[64][72];
    const int bid = blockIdx.x;
    const int tid = threadIdx.x;

    if (bid < 6144) {
        int gidx = bid * 256 + tid;                   // vec8 group
        int t    = gidx >> 19;
        int off  = (gidx & 0x7FFFF) * 8;
        const float* src = (t == 0) ? q : (t == 1) ? k : v;
        const float4 f0 = *(const float4*)&src[off];
        const float4 f1 = *(const float4*)&src[off + 4];
        bf16x8 p = { (bf16)f0.x, (bf16)f0.y, (bf16)f0.z, (bf16)f0.w,
                     (bf16)f1.x, (bf16)f1.y, (bf16)f1.z, (bf16)f1.w };
        *(bf16x8*)&Xcat[(size_t)gidx * 8] = p;
        return;
    }
    if (bid < 6912) {
        // W[h][k][e] fp32 -> Wqkv[t*1Mi + (h*64+e)*1024 + k]
        int idx = bid - 6144;                         // 768
        int x = idx & 15, z = idx >> 4;               // x: k-tile, z = t*16+h
        int t = z >> 4, h = z & 15;
        const float* inp = ((t == 0) ? Wq : (t == 1) ? Wk : Wv) + (size_t)h * 65536;
        bf16* outp = Wqkv + (size_t)t * 1024 * 1024 + (size_t)h * 65536;
        int r0 = x * 64;
        #pragma unroll
        for (int i = 0; i < 2; i++) {
            int s = tid + i * 256;
            int r = s >> 3, c8 = (s & 7) * 8;
            const float* ap = &inp[(size_t)(r0 + r) * 64 + c8];
            float4 f0 = *(const float4*)ap;
            float4 f1 = *(const float4*)(ap + 4);
            bf16x8 p = { (bf16)f0.x, (bf16)f0.y, (bf16)f0.z, (bf16)f0.w,
                         (bf16)f1.x, (bf16)f1.y, (bf16)f1.z, (bf16)f1.w };
            *(bf16x8*)&Tl[r][c8] = p;
        }
        __syncthreads();
        #pragma unroll
        for (int i = 0; i < 2; i++) {
            int s = tid + i * 256;
            int c = s >> 3, r8 = (s & 7) * 8;
            bf16x8 p;
            #pragma unroll
            for (int j = 0; j < 8; j++) p[j] = Tl[r8 + j][c];
            *(bf16x8*)&outp[(size_t)c * 1024 + r0 + r8] = p;
        }
        return;
    }
    // Wo[h][e][o] fp32 -> Wot[o][h*64+e]
    {
        int idx = bid - 6912;                         // 256
        int y = idx & 15, h = idx >> 4;
        int c0 = y * 64;
        const float* inp = Wo + (size_t)h * 65536;
        bf16* outp = Wot + (size_t)h * 64;
        #pragma unroll
        for (int i = 0; i < 2; i++) {
            int s = tid + i * 256;
            int r = s >> 3, c8 = (s & 7) * 8;
            const float* ap = &inp[(size_t)r * 1024 + c0 + c8];
            float4 f0 = *(const float4*)ap;
            float4 f1 = *(const float4*)(ap + 4);
            bf16x8 p = { (bf16)f0.x, (bf16)f0.y, (bf16)f0.z, (bf16)f0.w,
                         (bf16)f1.x, (bf16)f1.y, (bf16)f1.z, (bf16)f1.w };
            *(bf16x8*)&Tl[r][c8] = p;
        }
        __syncthreads();
        #pragma unroll
        for (int i = 0; i < 2; i++) {
            int s = tid + i * 256;
            int c = s >> 3, r8 = (s & 7) * 8;
            bf16x8 p;
            #pragma unroll
            for (int j = 0; j < 8; j++) p[j] = Tl[r8 + j][c];
            *(bf16x8*)&outp[(size_t)(c0 + c) * 1024 + r8] = p;
        }
    }
}

// ---------------------------------------------------------------------------
// Fused QKV projection GEMM: grid (96, 8); slab = blockIdx.x>>5 in {0,1,2}.
// slab 0 -> Qproj (scaled), slab 1 -> Kproj, slab 2 -> Vt transposed epilogue
// with the 32-block kv PERMUTATION: pos(s) = (s&~31) | ((s>>2)&3)*8 |
// ((s>>4)&1)*4 | (s&3), so attn V-fragments are contiguous b128 reads.
// Double-buffered LDS + stage(t+1)-before-compute(t) + one barrier per K-tile.
// ---------------------------------------------------------------------------
__global__ __launch_bounds__(256)
void qkv_gemm(const bf16* __restrict__ Xcat, const bf16* __restrict__ Wqkv,
              bf16* __restrict__ Cq, bf16* __restrict__ Ck, bf16* __restrict__ Vt,
              float qscale)
{
    __shared__ bf16 Al[2][128 * 64];
    __shared__ bf16 Bl[2][128 * 64];
    const int slab  = blockIdx.x >> 5;
    const int mbase = (blockIdx.x & 31) * 128;
    const int nbase = blockIdx.y * 128;
    const int tid = threadIdx.x;
    const int w = tid >> 6, lane = tid & 63;
    const int lm = lane & 15, q4 = lane >> 4;
    const int wr = (w >> 1) * 64, wc = (w & 1) * 64;
    const int lrow = lane >> 3, lsw = ((lane & 7) ^ lrow) * 8;

    const bf16* A  = Xcat + (size_t)slab * 4096 * 1024;
    const bf16* Bt = Wqkv + (size_t)slab * 1024 * 1024;

    f32x4 acc[4][4] = {};

    auto stage = [&](int k0, int d) {
        #pragma unroll
        for (int i = 0; i < 4; i++) {
            int c = w * 4 + i;
            gl2lds16(&A [(size_t)(mbase + c * 8 + lrow) * 1024 + k0 + lsw], &Al[d][c * 512]);
            gl2lds16(&Bt[(size_t)(nbase + c * 8 + lrow) * 1024 + k0 + lsw], &Bl[d][c * 512]);
        }
    };

    stage(0, 0);

    for (int t = 0; t < 16; t++) {
        __syncthreads();                      // buf[t&1] ready (loads had a full
        if (t < 15) stage((t + 1) * 64, (t + 1) & 1);   // compute phase to land)
        const bf16* Ad = &Al[t & 1][0];
        const bf16* Bd = &Bl[t & 1][0];
        __builtin_amdgcn_s_setprio(1);
        #pragma unroll
        for (int kk2 = 0; kk2 < 2; kk2++) {
            bf16x8 a[4], bfr[4];
            const int g = ((kk2 * 4 + q4) ^ (lm & 7)) * 8;
            #pragma unroll
            for (int i = 0; i < 4; i++) a[i]   = *(const bf16x8*)&Ad[(wr + i * 16 + lm) * 64 + g];
            #pragma unroll
            for (int j = 0; j < 4; j++) bfr[j] = *(const bf16x8*)&Bd[(wc + j * 16 + lm) * 64 + g];
            #pragma unroll
            for (int i = 0; i < 4; i++)
                #pragma unroll
                for (int j = 0; j < 4; j++)
                    acc[i][j] = MFMA16(a[i], bfr[j], acc[i][j]);
        }
        __builtin_amdgcn_s_setprio(0);
    }

    if (slab == 2) {
        #pragma unroll
        for (int i = 0; i < 4; i++)
            #pragma unroll
            for (int j = 0; j < 4; j++) {
                int s0  = mbase + wr + i * 16 + q4 * 4;      // kv, multiple of 4
                int col = nbase + wc + j * 16 + lm;          // e
                int sp  = (s0 & ~31) | (((s0 >> 2) & 3) * 8) | (((s0 >> 4) & 1) * 4);
                bf16x4 p = { (bf16)acc[i][j][0], (bf16)acc[i][j][1],
                             (bf16)acc[i][j][2], (bf16)acc[i][j][3] };
                *(bf16x4*)&Vt[(size_t)col * 4096 + sp] = p;
            }
    } else {
        bf16* C = (slab == 0) ? Cq : Ck;
        const float scale = (slab == 0) ? qscale : 1.0f;
        #pragma unroll
        for (int i = 0; i < 4; i++)
            #pragma unroll
            for (int j = 0; j < 4; j++)
                #pragma unroll
                for (int r = 0; r < 4; r++) {
                    int row = mbase + wr + i * 16 + q4 * 4 + r;
                    int col = nbase + wc + j * 16 + lm;
                    C[(size_t)row * 1024 + col] = (bf16)(acc[i][j][r] * scale);
                }
    }
}

// ---------------------------------------------------------------------------
// Output projection. Round-7: rebuilt as an exact clone of the qkv structure:
// 128x128 tiles (was 64x128 with a 12-ds_read-per-16-MFMA ratio = 0.75),
// acc[4][4] per wave (ratio 0.5), double-buffer + stage-before-compute,
// fp32 epilogue. Grid (32, 8) = 256 blocks = 1 block/CU (64 KB LDS).
// out[4096,1024] fp32 = Hd bf16 @ Wot^T
// ---------------------------------------------------------------------------
__global__ __launch_bounds__(256)
void outproj_gemm(const bf16* __restrict__ A, const bf16* __restrict__ Bt,
                  float* __restrict__ C)
{
    __shared__ bf16 Al[2][128 * 64];
    __shared__ bf16 Bl[2][128 * 64];
    const int mbase = blockIdx.x * 128;
    const int nbase = blockIdx.y * 128;
    const int tid = threadIdx.x;
    const int w = tid >> 6, lane = tid & 63;
    const int lm = lane & 15, q4 = lane >> 4;
    const int wr = (w >> 1) * 64, wc = (w & 1) * 64;
    const int lrow = lane >> 3, lsw = ((lane & 7) ^ lrow) * 8;

    f32x4 acc[4][4] = {};

    auto stage = [&](int k0, int d) {
        #pragma unroll
        for (int i = 0; i < 4; i++) {
            int c = w * 4 + i;
            gl2lds16(&A [(size_t)(mbase + c * 8 + lrow) * 1024 + k0 + lsw], &Al[d][c * 512]);
            gl2lds16(&Bt[(size_t)(nbase + c * 8 + lrow) * 1024 + k0 + lsw], &Bl[d][c * 512]);
        }
    };

    stage(0, 0);

    for (int t = 0; t < 16; t++) {
        __syncthreads();
        if (t < 15) stage((t + 1) * 64, (t + 1) & 1);
        const bf16* Ad = &Al[t & 1][0];
        const bf16* Bd = &Bl[t & 1][0];
        __builtin_amdgcn_s_setprio(1);
        #pragma unroll
        for (int kk2 = 0; kk2 < 2; kk2++) {
            bf16x8 a[4], bfr[4];
            const int g = ((kk2 * 4 + q4) ^ (lm & 7)) * 8;
            #pragma unroll
            for (int i = 0; i < 4; i++) a[i]   = *(const bf16x8*)&Ad[(wr + i * 16 + lm) * 64 + g];
            #pragma unroll
            for (int j = 0; j < 4; j++) bfr[j] = *(const bf16x8*)&Bd[(wc + j * 16 + lm) * 64 + g];
            #pragma unroll
            for (int i = 0; i < 4; i++)
                #pragma unroll
                for (int j = 0; j < 4; j++)
                    acc[i][j] = MFMA16(a[i], bfr[j], acc[i][j]);
        }
        __builtin_amdgcn_s_setprio(0);
    }

    #pragma unroll
    for (int i = 0; i < 4; i++)
        #pragma unroll
        for (int j = 0; j < 4; j++)
            #pragma unroll
            for (int r = 0; r < 4; r++) {
                int row = mbase + wr + i * 16 + q4 * 4 + r;
                int col = nbase + wc + j * 16 + lm;
                C[(size_t)row * 1024 + col] = acc[i][j][r];
            }
}

// ---------------------------------------------------------------------------
// Flash attention (round-5 version, 45.2 us — round-6 St-pipeline reverted:
// it raised VGPR 92->112, LDS 32.5->48.5 KB and the compiler did not
// interleave S(t+1) with exp(t); dur regressed 45->52.6).
// Per-wave footprint 64q x 32kv (4 q-strips): each K/V fragment feeds 4
// MFMAs; 8 ds_read_b128 per 18 MFMA. Block = 128 q rows: 4 waves =
// 2 q-groups (p) x 2 kv-halves (kvh). Grid (16,2,16) = 512 blocks = 2/CU.
//   Kept: XCD swizzle (512 = 8*64; each XCD owns 4 complete (b,h) groups),
//   kv-permuted Vt, XOR LDS swizzle, Lacc denom-via-MFMA, setprio,
//   double-buffer stage-before-compute, f32 LDS merge of kv-halves.
// ---------------------------------------------------------------------------
__global__ __launch_bounds__(256, 2)
void attn_kernel(const bf16* __restrict__ Qp, const bf16* __restrict__ Kp,
                 const bf16* __restrict__ Vt, bf16* __restrict__ Hd)
{
    __shared__ bf16 KV[4][64 * 64];     // [0,1]=K dbuf, [2,3]=V dbuf; 32 KB
    __shared__ float Ls[128];           // denom merge scratch

    // XCD-aware remap (8 XCDs, 512 blocks, bijective: 512 = 8*64)
    const int n  = blockIdx.x + 16 * (blockIdx.y + 2 * blockIdx.z);
    const int m  = (n & 7) * 64 + (n >> 3);
    const int qt = m & 15, bh = m >> 4;
    const int b  = bh & 1,  h  = bh >> 1;

    const int qbase = qt * 128;
    const int tid  = threadIdx.x;
    const int w    = tid >> 6, lane = tid & 63;
    const int p    = w & 1;          // q-group: rows [p*64, p*64+64)
    const int kvh  = w >> 1;         // kv half of each 64-wide tile
    const int lm   = lane & 15, q4 = lane >> 4;
    const int lrow = lane >> 3, lsw = ((lane & 7) ^ lrow) * 8;

    const bf16* Qh = Qp + (size_t)(b * 2048 + qbase + p * 64) * 1024 + h * 64;
    const bf16* Kh = Kp + (size_t)(b * 2048) * 1024 + h * 64;
    const bf16* Vh = Vt + (size_t)(h * 64) * 4096 + b * 2048;

    // Q fragments (loop-invariant), B-operand layout: n=lm, k=q4*8+j
    bf16x8 Qf[4][2];
    #pragma unroll
    for (int i = 0; i < 4; i++)
        #pragma unroll
        for (int kk2 = 0; kk2 < 2; kk2++)
            Qf[i][kk2] = *(const bf16x8*)&Qh[(size_t)(i * 16 + lm) * 1024 + kk2 * 32 + q4 * 8];

    const bf16 one = (bf16)1.0f;
    const bf16x8 ones = { one, one, one, one, one, one, one, one };

    f32x4 O[4][4] = {};
    f32x4 Lacc[4] = {};   // row-sums of P (softmax denom), same row layout as O

    // stage kv-tile kt into buffer d (K rows=kv, V rows=e; identical pattern)
    auto stage = [&](int kt, int d) {
        #pragma unroll
        for (int i = 0; i < 2; i++) {
            int c = w * 2 + i;                           // 8 chunks of 8 rows
            gl2lds16(&Kh[(size_t)(kt * 64 + c * 8 + lrow) * 1024 + lsw], &KV[d][c * 512]);
            gl2lds16(&Vh[(size_t)(c * 8 + lrow) * 4096 + kt * 64 + lsw], &KV[2 + d][c * 512]);
        }
    };

    stage(0, 0);

    for (int it = 0; it < 32; it++) {
        __syncthreads();                                 // buf[it&1] ready
        if (it < 31) stage(it + 1, (it + 1) & 1);        // overlap with compute
        const bf16* Kd = &KV[it & 1][0];
        const bf16* Vd = &KV[2 + (it & 1)][0];

        // S^T for this wave's kv-half: ctp in {kvh*2, kvh*2+1}; 4 q-strips
        f32x4 St[4][2] = {};
        __builtin_amdgcn_s_setprio(1);
        #pragma unroll
        for (int c2 = 0; c2 < 2; c2++) {
            const int ctp = kvh * 2 + c2;
            #pragma unroll
            for (int kk2 = 0; kk2 < 2; kk2++) {
                const int g = ((kk2 * 4 + q4) ^ (lm & 7)) * 8;
                bf16x8 kf = *(const bf16x8*)&Kd[(ctp * 16 + lm) * 64 + g];
                #pragma unroll
                for (int i = 0; i < 4; i++)
                    St[i][c2] = MFMA16(kf, Qf[i][kk2], St[i][c2]);
            }
        }
        __builtin_amdgcn_s_setprio(0);

        // P = exp2(S^T) packed into A-slots for this kv-32 chunk
        bf16x8 Pf[4];
        #pragma unroll
        for (int i = 0; i < 4; i++)
            #pragma unroll
            for (int j = 0; j < 8; j++)
                Pf[i][j] = (bf16)__builtin_amdgcn_exp2f(St[i][j >> 2][j & 3]);

        __builtin_amdgcn_s_setprio(1);
        #pragma unroll
        for (int i = 0; i < 4; i++) Lacc[i] = MFMA16(Pf[i], ones, Lacc[i]);
        const int gv = ((kvh * 4 + q4) ^ (lm & 7)) * 8;
        #pragma unroll
        for (int et = 0; et < 4; et++) {
            bf16x8 vf = *(const bf16x8*)&Vd[(et * 16 + lm) * 64 + gv];
            #pragma unroll
            for (int i = 0; i < 4; i++)
                O[i][et] = MFMA16(Pf[i], vf, O[i][et]);
        }
        __builtin_amdgcn_s_setprio(0);
    }

    // ---- merge the two kv-halves via LDS (Ol aliases all of KV: 32 KB) ----
    __syncthreads();                       // last tile's reads done
    float* Ol = (float*)&KV[0][0];         // [p][64 rows][64 cols] f32
    if (kvh == 1) {
        #pragma unroll
        for (int i = 0; i < 4; i++)
            #pragma unroll
            for (int et = 0; et < 4; et++)
                #pragma unroll
                for (int r = 0; r < 4; r++)
                    Ol[(p * 64 + i * 16 + q4 * 4 + r) * 64 + et * 16 + lm] = O[i][et][r];
        if (lm == 0) {
            #pragma unroll
            for (int i = 0; i < 4; i++)
                #pragma unroll
                for (int r = 0; r < 4; r++)
                    Ls[p * 64 + i * 16 + q4 * 4 + r] = Lacc[i][r];
        }
    }
    __syncthreads();
    if (kvh == 0) {
        #pragma unroll
        for (int i = 0; i < 4; i++) {
            float rl[4];
            #pragma unroll
            for (int r = 0; r < 4; r++)
                rl[r] = 1.0f / (Lacc[i][r] + Ls[p * 64 + i * 16 + q4 * 4 + r]);
            #pragma unroll
            for (int et = 0; et < 4; et++)
                #pragma unroll
                for (int r = 0; r < 4; r++) {
                    float o = O[i][et][r] +
                              Ol[(p * 64 + i * 16 + q4 * 4 + r) * 64 + et * 16 + lm];
                    int row = b * 2048 + qbase + p * 64 + i * 16 + q4 * 4 + r;
                    Hd[(size_t)row * 1024 + h * 64 + et * 16 + lm] = (bf16)(o * rl[r]);
                }
        }
    }
}

extern "C" void kernel_launch(void* const* d_in, const int* in_sizes, int n_in,
                              void* d_out, int out_size, void* d_ws, size_t ws_size,
                              hipStream_t stream)
{
    const float* q  = (const float*)d_in[0];
    const float* k  = (const float*)d_in[1];
    const float* v  = (const float*)d_in[2];
    const float* Wq = (const float*)d_in[3];
    const float* Wk = (const float*)d_in[4];
    const float* Wv = (const float*)d_in[5];
    const float* Wo = (const float*)d_in[6];
    float* out = (float*)d_out;

    // ws (bf16 elems, Mi = 1024*1024; 24Mi = 48 MB):
    //  [ 0, 4) qb -> Hd (attn out; qb dead after qkv_gemm)   [ 4, 8) kb
    //  [ 8,12) vb    [12,15) Wqkv   [15,16) Wot   [16,20) Qproj   [20,24) Kproj
    // Vt (bf16, 8 MB, kv-permuted) lives in d_out (16 MB fp32), overwritten
    // by outproj at the very end.
    const size_t Mi = 1024 * 1024;
    bf16* Xcat  = (bf16*)d_ws;
    bf16* Hd    = Xcat;                   // alias qb
    bf16* Wqkv  = Xcat + 12 * Mi;
    bf16* Wot   = Xcat + 15 * Mi;
    bf16* Qproj = Xcat + 16 * Mi;
    bf16* Kproj = Xcat + 20 * Mi;
    bf16* Vtb   = (bf16*)d_out;

    const float qscale = 0.125f * 1.4426950408889634f;  // 1/sqrt(64) * log2(e)

    prep_kernel<<<7168, 256, 0, stream>>>(q, k, v, Wq, Wk, Wv, Wo, Xcat, Wqkv, Wot);
    qkv_gemm<<<dim3(96, 8), 256, 0, stream>>>(Xcat, Wqkv, Qproj, Kproj, Vtb, qscale);
    attn_kernel<<<dim3(16, 2, 16), 256, 0, stream>>>(Qproj, Kproj, Vtb, Hd);
    outproj_gemm<<<dim3(32, 8), 256, 0, stream>>>(Hd, Wot, out);
}

// Round 8
// 197.917 us; speedup vs baseline: 1.0453x; 1.0453x over previous
//
#include <hip/hip_runtime.h>
#include <hip/hip_bf16.h>

typedef __bf16 bf16;
typedef __bf16 bf16x8 __attribute__((ext_vector_type(8)));
typedef __bf16 bf16x4 __attribute__((ext_vector_type(4)));
typedef float  f32x4  __attribute__((ext_vector_type(4)));

#define MFMA16(a,b,c) __builtin_amdgcn_mfma_f32_16x16x32_bf16(a, b, c, 0, 0, 0)

// async global->LDS, 16B per lane; lds dst is wave-uniform base + lane*16
__device__ __forceinline__ void gl2lds16(const bf16* g, bf16* l) {
    __builtin_amdgcn_global_load_lds(
        (__attribute__((address_space(1))) void*)g,
        (__attribute__((address_space(3))) void*)l, 16, 0, 0);
}

// ---------------------------------------------------------------------------
// Fused prep: blocks [0,6144) fp32->bf16 cvt of q|k|v; [6144,6912) Wq/Wk/Wv
// transpose; [6912,7168) Wo transpose.
// ---------------------------------------------------------------------------
__global__ __launch_bounds__(256)
void prep_kernel(const float* __restrict__ q, const float* __restrict__ k,
                 const float* __restrict__ v, const float* __restrict__ Wq,
                 const float* __restrict__ Wk, const float* __restrict__ Wv,
                 const float* __restrict__ Wo, bf16* __restrict__ Xcat,
                 bf16* __restrict__ Wqkv, bf16* __restrict__ Wot)
{
    __shared__ bf16 Tl[64][72];
    const int bid = blockIdx.x;
    const int tid = threadIdx.x;

    if (bid < 6144) {
        int gidx = bid * 256 + tid;                   // vec8 group
        int t    = gidx >> 19;
        int off  = (gidx & 0x7FFFF) * 8;
        const float* src = (t == 0) ? q : (t == 1) ? k : v;
        const float4 f0 = *(const float4*)&src[off];
        const float4 f1 = *(const float4*)&src[off + 4];
        bf16x8 p = { (bf16)f0.x, (bf16)f0.y, (bf16)f0.z, (bf16)f0.w,
                     (bf16)f1.x, (bf16)f1.y, (bf16)f1.z, (bf16)f1.w };
        *(bf16x8*)&Xcat[(size_t)gidx * 8] = p;
        return;
    }
    if (bid < 6912) {
        // W[h][k][e] fp32 -> Wqkv[t*1Mi + (h*64+e)*1024 + k]
        int idx = bid - 6144;                         // 768
        int x = idx & 15, z = idx >> 4;               // x: k-tile, z = t*16+h
        int t = z >> 4, h = z & 15;
        const float* inp = ((t == 0) ? Wq : (t == 1) ? Wk : Wv) + (size_t)h * 65536;
        bf16* outp = Wqkv + (size_t)t * 1024 * 1024 + (size_t)h * 65536;
        int r0 = x * 64;
        #pragma unroll
        for (int i = 0; i < 2; i++) {
            int s = tid + i * 256;
            int r = s >> 3, c8 = (s & 7) * 8;
            const float* ap = &inp[(size_t)(r0 + r) * 64 + c8];
            float4 f0 = *(const float4*)ap;
            float4 f1 = *(const float4*)(ap + 4);
            bf16x8 p = { (bf16)f0.x, (bf16)f0.y, (bf16)f0.z, (bf16)f0.w,
                         (bf16)f1.x, (bf16)f1.y, (bf16)f1.z, (bf16)f1.w };
            *(bf16x8*)&Tl[r][c8] = p;
        }
        __syncthreads();
        #pragma unroll
        for (int i = 0; i < 2; i++) {
            int s = tid + i * 256;
            int c = s >> 3, r8 = (s & 7) * 8;
            bf16x8 p;
            #pragma unroll
            for (int j = 0; j < 8; j++) p[j] = Tl[r8 + j][c];
            *(bf16x8*)&outp[(size_t)c * 1024 + r0 + r8] = p;
        }
        return;
    }
    // Wo[h][e][o] fp32 -> Wot[o][h*64+e]
    {
        int idx = bid - 6912;                         // 256
        int y = idx & 15, h = idx >> 4;
        int c0 = y * 64;
        const float* inp = Wo + (size_t)h * 65536;
        bf16* outp = Wot + (size_t)h * 64;
        #pragma unroll
        for (int i = 0; i < 2; i++) {
            int s = tid + i * 256;
            int r = s >> 3, c8 = (s & 7) * 8;
            const float* ap = &inp[(size_t)r * 1024 + c0 + c8];
            float4 f0 = *(const float4*)ap;
            float4 f1 = *(const float4*)(ap + 4);
            bf16x8 p = { (bf16)f0.x, (bf16)f0.y, (bf16)f0.z, (bf16)f0.w,
                         (bf16)f1.x, (bf16)f1.y, (bf16)f1.z, (bf16)f1.w };
            *(bf16x8*)&Tl[r][c8] = p;
        }
        __syncthreads();
        #pragma unroll
        for (int i = 0; i < 2; i++) {
            int s = tid + i * 256;
            int c = s >> 3, r8 = (s & 7) * 8;
            bf16x8 p;
            #pragma unroll
            for (int j = 0; j < 8; j++) p[j] = Tl[r8 + j][c];
            *(bf16x8*)&outp[(size_t)(c0 + c) * 1024 + r8] = p;
        }
    }
}

// ---------------------------------------------------------------------------
// Fused QKV projection GEMM: grid (96, 8); slab = blockIdx.x>>5 in {0,1,2}.
// slab 0 -> Qproj (scaled), slab 1 -> Kproj, slab 2 -> Vt transposed epilogue
// with the 32-block kv PERMUTATION (attn V-frags contiguous b128 reads).
// Round-8: BK 64 -> 32. LDS 64 -> 32 KB/block so 3 blocks/CU (was 2) -- the
// r4 double-buffer at 64 KB lost the 3rd block; BK=32 keeps the 8-read:16-MFMA
// ratio and recovers cross-block overlap during barrier drains.
// New 32-col swizzle: LDS colgrp = q4 ^ ((row>>1)&3), i.e. 8 distinct
// (row-parity, cg) bank-spans per wave (same conflict profile as BK=64's
// (lm&7)-XOR); staging source pre-swizzled with the same involution.
// ---------------------------------------------------------------------------
__global__ __launch_bounds__(256)
void qkv_gemm(const bf16* __restrict__ Xcat, const bf16* __restrict__ Wqkv,
              bf16* __restrict__ Cq, bf16* __restrict__ Ck, bf16* __restrict__ Vt,
              float qscale)
{
    __shared__ bf16 Al[2][128 * 32];
    __shared__ bf16 Bl[2][128 * 32];
    const int slab  = blockIdx.x >> 5;
    const int mbase = (blockIdx.x & 31) * 128;
    const int nbase = blockIdx.y * 128;
    const int tid = threadIdx.x;
    const int w = tid >> 6, lane = tid & 63;
    const int lm = lane & 15, q4 = lane >> 4;
    const int wr = (w >> 1) * 64, wc = (w & 1) * 64;
    const int lrow = lane >> 2;                          // 16 rows / wave-chunk
    const int lsw  = ((lane & 3) ^ ((lane >> 3) & 3)) * 8;  // src col swizzle

    const bf16* A  = Xcat + (size_t)slab * 4096 * 1024;
    const bf16* Bt = Wqkv + (size_t)slab * 1024 * 1024;

    f32x4 acc[4][4] = {};

    auto stage = [&](int k0, int d) {
        #pragma unroll
        for (int i = 0; i < 2; i++) {
            int c = w * 2 + i;                           // 8 chunks of 16 rows
            gl2lds16(&A [(size_t)(mbase + c * 16 + lrow) * 1024 + k0 + lsw], &Al[d][c * 512]);
            gl2lds16(&Bt[(size_t)(nbase + c * 16 + lrow) * 1024 + k0 + lsw], &Bl[d][c * 512]);
        }
    };

    stage(0, 0);

    for (int t = 0; t < 32; t++) {
        __syncthreads();                      // buf[t&1] ready (loads had a full
        if (t < 31) stage((t + 1) * 32, (t + 1) & 1);   // compute phase to land)
        const bf16* Ad = &Al[t & 1][0];
        const bf16* Bd = &Bl[t & 1][0];
        __builtin_amdgcn_s_setprio(1);
        {
            bf16x8 a[4], bfr[4];
            const int g = (q4 ^ ((lm >> 1) & 3)) * 8;    // matches staging swz
            #pragma unroll
            for (int i = 0; i < 4; i++) a[i]   = *(const bf16x8*)&Ad[(wr + i * 16 + lm) * 32 + g];
            #pragma unroll
            for (int j = 0; j < 4; j++) bfr[j] = *(const bf16x8*)&Bd[(wc + j * 16 + lm) * 32 + g];
            #pragma unroll
            for (int i = 0; i < 4; i++)
                #pragma unroll
                for (int j = 0; j < 4; j++)
                    acc[i][j] = MFMA16(a[i], bfr[j], acc[i][j]);
        }
        __builtin_amdgcn_s_setprio(0);
    }

    if (slab == 2) {
        #pragma unroll
        for (int i = 0; i < 4; i++)
            #pragma unroll
            for (int j = 0; j < 4; j++) {
                int s0  = mbase + wr + i * 16 + q4 * 4;      // kv, multiple of 4
                int col = nbase + wc + j * 16 + lm;          // e
                int sp  = (s0 & ~31) | (((s0 >> 2) & 3) * 8) | (((s0 >> 4) & 1) * 4);
                bf16x4 p = { (bf16)acc[i][j][0], (bf16)acc[i][j][1],
                             (bf16)acc[i][j][2], (bf16)acc[i][j][3] };
                *(bf16x4*)&Vt[(size_t)col * 4096 + sp] = p;
            }
    } else {
        bf16* C = (slab == 0) ? Cq : Ck;
        const float scale = (slab == 0) ? qscale : 1.0f;
        #pragma unroll
        for (int i = 0; i < 4; i++)
            #pragma unroll
            for (int j = 0; j < 4; j++)
                #pragma unroll
                for (int r = 0; r < 4; r++) {
                    int row = mbase + wr + i * 16 + q4 * 4 + r;
                    int col = nbase + wc + j * 16 + lm;
                    C[(size_t)row * 1024 + col] = (bf16)(acc[i][j][r] * scale);
                }
    }
}

// ---------------------------------------------------------------------------
// Output projection, 64x128 (MxN) tiles, grid (64, 8) = 2 blocks/CU
// (round-6 version restored: the r7 128x128 rebuild grid-capped itself to
// 1 block/CU -- no cross-block cover during barrier drains -> regression).
// out[4096,1024] fp32 = Hd bf16 @ Wot^T. Double-buffered schedule.
// ---------------------------------------------------------------------------
__global__ __launch_bounds__(256)
void outproj_gemm(const bf16* __restrict__ A, const bf16* __restrict__ Bt,
                  float* __restrict__ C)
{
    __shared__ bf16 Al[2][64 * 64];
    __shared__ bf16 Bl[2][128 * 64];
    const int mbase = blockIdx.x * 64;
    const int nbase = blockIdx.y * 128;
    const int tid = threadIdx.x;
    const int w = tid >> 6, lane = tid & 63;
    const int lm = lane & 15, q4 = lane >> 4;
    const int wm = (w >> 1) * 32, wn = (w & 1) * 64;   // 32x64 per wave
    const int lrow = lane >> 3, lsw = ((lane & 7) ^ lrow) * 8;

    f32x4 acc[2][4] = {};

    auto stage = [&](int k0, int d) {
        #pragma unroll
        for (int i = 0; i < 2; i++) {
            int c = w * 2 + i;                          // 8 chunks of 8 rows
            gl2lds16(&A[(size_t)(mbase + c * 8 + lrow) * 1024 + k0 + lsw], &Al[d][c * 512]);
        }
        #pragma unroll
        for (int i = 0; i < 4; i++) {
            int c = w * 4 + i;                          // 16 chunks of 8 rows
            gl2lds16(&Bt[(size_t)(nbase + c * 8 + lrow) * 1024 + k0 + lsw], &Bl[d][c * 512]);
        }
    };

    stage(0, 0);

    for (int t = 0; t < 16; t++) {
        __syncthreads();
        if (t < 15) stage((t + 1) * 64, (t + 1) & 1);
        const bf16* Ad = &Al[t & 1][0];
        const bf16* Bd = &Bl[t & 1][0];
        __builtin_amdgcn_s_setprio(1);
        #pragma unroll
        for (int kk2 = 0; kk2 < 2; kk2++) {
            bf16x8 a[2], bfr[4];
            const int g = ((kk2 * 4 + q4) ^ (lm & 7)) * 8;
            #pragma unroll
            for (int i = 0; i < 2; i++) a[i]   = *(const bf16x8*)&Ad[(wm + i * 16 + lm) * 64 + g];
            #pragma unroll
            for (int j = 0; j < 4; j++) bfr[j] = *(const bf16x8*)&Bd[(wn + j * 16 + lm) * 64 + g];
            #pragma unroll
            for (int i = 0; i < 2; i++)
                #pragma unroll
                for (int j = 0; j < 4; j++)
                    acc[i][j] = MFMA16(a[i], bfr[j], acc[i][j]);
        }
        __builtin_amdgcn_s_setprio(0);
    }

    #pragma unroll
    for (int i = 0; i < 2; i++)
        #pragma unroll
        for (int j = 0; j < 4; j++)
            #pragma unroll
            for (int r = 0; r < 4; r++) {
                int row = mbase + wm + i * 16 + q4 * 4 + r;
                int col = nbase + wn + j * 16 + lm;
                C[(size_t)row * 1024 + col] = acc[i][j][r];
            }
}

// ---------------------------------------------------------------------------
// Flash attention (round-5 version, ~46 us).
// Per-wave footprint 64q x 32kv (4 q-strips): each K/V fragment feeds 4
// MFMAs; 8 ds_read_b128 per 18 MFMA. Block = 128 q rows: 4 waves =
// 2 q-groups (p) x 2 kv-halves (kvh). Grid (16,2,16) = 512 blocks = 2/CU.
//   Kept: XCD swizzle (512 = 8*64; each XCD owns 4 complete (b,h) groups),
//   kv-permuted Vt, XOR LDS swizzle, Lacc denom-via-MFMA, setprio,
//   double-buffer stage-before-compute, f32 LDS merge of kv-halves.
// ---------------------------------------------------------------------------
__global__ __launch_bounds__(256, 2)
void attn_kernel(const bf16* __restrict__ Qp, const bf16* __restrict__ Kp,
                 const bf16* __restrict__ Vt, bf16* __restrict__ Hd)
{
    __shared__ bf16 KV[4][64 * 64];     // [0,1]=K dbuf, [2,3]=V dbuf; 32 KB
    __shared__ float Ls[128];           // denom merge scratch

    // XCD-aware remap (8 XCDs, 512 blocks, bijective: 512 = 8*64)
    const int n  = blockIdx.x + 16 * (blockIdx.y + 2 * blockIdx.z);
    const int m  = (n & 7) * 64 + (n >> 3);
    const int qt = m & 15, bh = m >> 4;
    const int b  = bh & 1,  h  = bh >> 1;

    const int qbase = qt * 128;
    const int tid  = threadIdx.x;
    const int w    = tid >> 6, lane = tid & 63;
    const int p    = w & 1;          // q-group: rows [p*64, p*64+64)
    const int kvh  = w >> 1;         // kv half of each 64-wide tile
    const int lm   = lane & 15, q4 = lane >> 4;
    const int lrow = lane >> 3, lsw = ((lane & 7) ^ lrow) * 8;

    const bf16* Qh = Qp + (size_t)(b * 2048 + qbase + p * 64) * 1024 + h * 64;
    const bf16* Kh = Kp + (size_t)(b * 2048) * 1024 + h * 64;
    const bf16* Vh = Vt + (size_t)(h * 64) * 4096 + b * 2048;

    // Q fragments (loop-invariant), B-operand layout: n=lm, k=q4*8+j
    bf16x8 Qf[4][2];
    #pragma unroll
    for (int i = 0; i < 4; i++)
        #pragma unroll
        for (int kk2 = 0; kk2 < 2; kk2++)
            Qf[i][kk2] = *(const bf16x8*)&Qh[(size_t)(i * 16 + lm) * 1024 + kk2 * 32 + q4 * 8];

    const bf16 one = (bf16)1.0f;
    const bf16x8 ones = { one, one, one, one, one, one, one, one };

    f32x4 O[4][4] = {};
    f32x4 Lacc[4] = {};   // row-sums of P (softmax denom), same row layout as O

    // stage kv-tile kt into buffer d (K rows=kv, V rows=e; identical pattern)
    auto stage = [&](int kt, int d) {
        #pragma unroll
        for (int i = 0; i < 2; i++) {
            int c = w * 2 + i;                           // 8 chunks of 8 rows
            gl2lds16(&Kh[(size_t)(kt * 64 + c * 8 + lrow) * 1024 + lsw], &KV[d][c * 512]);
            gl2lds16(&Vh[(size_t)(c * 8 + lrow) * 4096 + kt * 64 + lsw], &KV[2 + d][c * 512]);
        }
    };

    stage(0, 0);

    for (int it = 0; it < 32; it++) {
        __syncthreads();                                 // buf[it&1] ready
        if (it < 31) stage(it + 1, (it + 1) & 1);        // overlap with compute
        const bf16* Kd = &KV[it & 1][0];
        const bf16* Vd = &KV[2 + (it & 1)][0];

        // S^T for this wave's kv-half: ctp in {kvh*2, kvh*2+1}; 4 q-strips
        f32x4 St[4][2] = {};
        __builtin_amdgcn_s_setprio(1);
        #pragma unroll
        for (int c2 = 0; c2 < 2; c2++) {
            const int ctp = kvh * 2 + c2;
            #pragma unroll
            for (int kk2 = 0; kk2 < 2; kk2++) {
                const int g = ((kk2 * 4 + q4) ^ (lm & 7)) * 8;
                bf16x8 kf = *(const bf16x8*)&Kd[(ctp * 16 + lm) * 64 + g];
                #pragma unroll
                for (int i = 0; i < 4; i++)
                    St[i][c2] = MFMA16(kf, Qf[i][kk2], St[i][c2]);
            }
        }
        __builtin_amdgcn_s_setprio(0);

        // P = exp2(S^T) packed into A-slots for this kv-32 chunk
        bf16x8 Pf[4];
        #pragma unroll
        for (int i = 0; i < 4; i++)
            #pragma unroll
            for (int j = 0; j < 8; j++)
                Pf[i][j] = (bf16)__builtin_amdgcn_exp2f(St[i][j >> 2][j & 3]);

        __builtin_amdgcn_s_setprio(1);
        #pragma unroll
        for (int i = 0; i < 4; i++) Lacc[i] = MFMA16(Pf[i], ones, Lacc[i]);
        const int gv = ((kvh * 4 + q4) ^ (lm & 7)) * 8;
        #pragma unroll
        for (int et = 0; et < 4; et++) {
            bf16x8 vf = *(const bf16x8*)&Vd[(et * 16 + lm) * 64 + gv];
            #pragma unroll
            for (int i = 0; i < 4; i++)
                O[i][et] = MFMA16(Pf[i], vf, O[i][et]);
        }
        __builtin_amdgcn_s_setprio(0);
    }

    // ---- merge the two kv-halves via LDS (Ol aliases all of KV: 32 KB) ----
    __syncthreads();                       // last tile's reads done
    float* Ol = (float*)&KV[0][0];         // [p][64 rows][64 cols] f32
    if (kvh == 1) {
        #pragma unroll
        for (int i = 0; i < 4; i++)
            #pragma unroll
            for (int et = 0; et < 4; et++)
                #pragma unroll
                for (int r = 0; r < 4; r++)
                    Ol[(p * 64 + i * 16 + q4 * 4 + r) * 64 + et * 16 + lm] = O[i][et][r];
        if (lm == 0) {
            #pragma unroll
            for (int i = 0; i < 4; i++)
                #pragma unroll
                for (int r = 0; r < 4; r++)
                    Ls[p * 64 + i * 16 + q4 * 4 + r] = Lacc[i][r];
        }
    }
    __syncthreads();
    if (kvh == 0) {
        #pragma unroll
        for (int i = 0; i < 4; i++) {
            float rl[4];
            #pragma unroll
            for (int r = 0; r < 4; r++)
                rl[r] = 1.0f / (Lacc[i][r] + Ls[p * 64 + i * 16 + q4 * 4 + r]);
            #pragma unroll
            for (int et = 0; et < 4; et++)
                #pragma unroll
                for (int r = 0; r < 4; r++) {
                    float o = O[i][et][r] +
                              Ol[(p * 64 + i * 16 + q4 * 4 + r) * 64 + et * 16 + lm];
                    int row = b * 2048 + qbase + p * 64 + i * 16 + q4 * 4 + r;
                    Hd[(size_t)row * 1024 + h * 64 + et * 16 + lm] = (bf16)(o * rl[r]);
                }
        }
    }
}

extern "C" void kernel_launch(void* const* d_in, const int* in_sizes, int n_in,
                              void* d_out, int out_size, void* d_ws, size_t ws_size,
                              hipStream_t stream)
{
    const float* q  = (const float*)d_in[0];
    const float* k  = (const float*)d_in[1];
    const float* v  = (const float*)d_in[2];
    const float* Wq = (const float*)d_in[3];
    const float* Wk = (const float*)d_in[4];
    const float* Wv = (const float*)d_in[5];
    const float* Wo = (const float*)d_in[6];
    float* out = (float*)d_out;

    // ws (bf16 elems, Mi = 1024*1024; 24Mi = 48 MB):
    //  [ 0, 4) qb -> Hd (attn out; qb dead after qkv_gemm)   [ 4, 8) kb
    //  [ 8,12) vb    [12,15) Wqkv   [15,16) Wot   [16,20) Qproj   [20,24) Kproj
    // Vt (bf16, 8 MB, kv-permuted) lives in d_out (16 MB fp32), overwritten
    // by outproj at the very end.
    const size_t Mi = 1024 * 1024;
    bf16* Xcat  = (bf16*)d_ws;
    bf16* Hd    = Xcat;                   // alias qb
    bf16* Wqkv  = Xcat + 12 * Mi;
    bf16* Wot   = Xcat + 15 * Mi;
    bf16* Qproj = Xcat + 16 * Mi;
    bf16* Kproj = Xcat + 20 * Mi;
    bf16* Vtb   = (bf16*)d_out;

    const float qscale = 0.125f * 1.4426950408889634f;  // 1/sqrt(64) * log2(e)

    prep_kernel<<<7168, 256, 0, stream>>>(q, k, v, Wq, Wk, Wv, Wo, Xcat, Wqkv, Wot);
    qkv_gemm<<<dim3(96, 8), 256, 0, stream>>>(Xcat, Wqkv, Qproj, Kproj, Vtb, qscale);
    attn_kernel<<<dim3(16, 2, 16), 256, 0, stream>>>(Qproj, Kproj, Vtb, Hd);
    outproj_gemm<<<dim3(64, 8), 256, 0, stream>>>(Hd, Wot, out);
}

// Round 9
// 197.253 us; speedup vs baseline: 1.0489x; 1.0034x over previous
//
#include <hip/hip_runtime.h>
#include <hip/hip_bf16.h>

typedef __bf16 bf16;
typedef __bf16 bf16x8 __attribute__((ext_vector_type(8)));
typedef __bf16 bf16x4 __attribute__((ext_vector_type(4)));
typedef float  f32x4  __attribute__((ext_vector_type(4)));

#define MFMA16(a,b,c) __builtin_amdgcn_mfma_f32_16x16x32_bf16(a, b, c, 0, 0, 0)

// async global->LDS, 16B per lane; lds dst is wave-uniform base + lane*16
__device__ __forceinline__ void gl2lds16(const bf16* g, bf16* l) {
    __builtin_amdgcn_global_load_lds(
        (__attribute__((address_space(1))) void*)g,
        (__attribute__((address_space(3))) void*)l, 16, 0, 0);
}

// ---------------------------------------------------------------------------
// Fused prep: blocks [0,6144) fp32->bf16 cvt of q|k|v; [6144,6912) Wq/Wk/Wv
// transpose; [6912,7168) Wo transpose.
// ---------------------------------------------------------------------------
__global__ __launch_bounds__(256)
void prep_kernel(const float* __restrict__ q, const float* __restrict__ k,
                 const float* __restrict__ v, const float* __restrict__ Wq,
                 const float* __restrict__ Wk, const float* __restrict__ Wv,
                 const float* __restrict__ Wo, bf16* __restrict__ Xcat,
                 bf16* __restrict__ Wqkv, bf16* __restrict__ Wot)
{
    __shared__ bf16 Tl[64][72];
    const int bid = blockIdx.x;
    const int tid = threadIdx.x;

    if (bid < 6144) {
        int gidx = bid * 256 + tid;                   // vec8 group
        int t    = gidx >> 19;
        int off  = (gidx & 0x7FFFF) * 8;
        const float* src = (t == 0) ? q : (t == 1) ? k : v;
        const float4 f0 = *(const float4*)&src[off];
        const float4 f1 = *(const float4*)&src[off + 4];
        bf16x8 p = { (bf16)f0.x, (bf16)f0.y, (bf16)f0.z, (bf16)f0.w,
                     (bf16)f1.x, (bf16)f1.y, (bf16)f1.z, (bf16)f1.w };
        *(bf16x8*)&Xcat[(size_t)gidx * 8] = p;
        return;
    }
    if (bid < 6912) {
        // W[h][k][e] fp32 -> Wqkv[t*1Mi + (h*64+e)*1024 + k]
        int idx = bid - 6144;                         // 768
        int x = idx & 15, z = idx >> 4;               // x: k-tile, z = t*16+h
        int t = z >> 4, h = z & 15;
        const float* inp = ((t == 0) ? Wq : (t == 1) ? Wk : Wv) + (size_t)h * 65536;
        bf16* outp = Wqkv + (size_t)t * 1024 * 1024 + (size_t)h * 65536;
        int r0 = x * 64;
        #pragma unroll
        for (int i = 0; i < 2; i++) {
            int s = tid + i * 256;
            int r = s >> 3, c8 = (s & 7) * 8;
            const float* ap = &inp[(size_t)(r0 + r) * 64 + c8];
            float4 f0 = *(const float4*)ap;
            float4 f1 = *(const float4*)(ap + 4);
            bf16x8 p = { (bf16)f0.x, (bf16)f0.y, (bf16)f0.z, (bf16)f0.w,
                         (bf16)f1.x, (bf16)f1.y, (bf16)f1.z, (bf16)f1.w };
            *(bf16x8*)&Tl[r][c8] = p;
        }
        __syncthreads();
        #pragma unroll
        for (int i = 0; i < 2; i++) {
            int s = tid + i * 256;
            int c = s >> 3, r8 = (s & 7) * 8;
            bf16x8 p;
            #pragma unroll
            for (int j = 0; j < 8; j++) p[j] = Tl[r8 + j][c];
            *(bf16x8*)&outp[(size_t)c * 1024 + r0 + r8] = p;
        }
        return;
    }
    // Wo[h][e][o] fp32 -> Wot[o][h*64+e]
    {
        int idx = bid - 6912;                         // 256
        int y = idx & 15, h = idx >> 4;
        int c0 = y * 64;
        const float* inp = Wo + (size_t)h * 65536;
        bf16* outp = Wot + (size_t)h * 64;
        #pragma unroll
        for (int i = 0; i < 2; i++) {
            int s = tid + i * 256;
            int r = s >> 3, c8 = (s & 7) * 8;
            const float* ap = &inp[(size_t)r * 1024 + c0 + c8];
            float4 f0 = *(const float4*)ap;
            float4 f1 = *(const float4*)(ap + 4);
            bf16x8 p = { (bf16)f0.x, (bf16)f0.y, (bf16)f0.z, (bf16)f0.w,
                         (bf16)f1.x, (bf16)f1.y, (bf16)f1.z, (bf16)f1.w };
            *(bf16x8*)&Tl[r][c8] = p;
        }
        __syncthreads();
        #pragma unroll
        for (int i = 0; i < 2; i++) {
            int s = tid + i * 256;
            int c = s >> 3, r8 = (s & 7) * 8;
            bf16x8 p;
            #pragma unroll
            for (int j = 0; j < 8; j++) p[j] = Tl[r8 + j][c];
            *(bf16x8*)&outp[(size_t)(c0 + c) * 1024 + r8] = p;
        }
    }
}

// ---------------------------------------------------------------------------
// Fused QKV projection GEMM: grid (96, 8); slab = blockIdx.x>>5 in {0,1,2}.
// slab 0 -> Qproj (scaled), slab 1 -> Kproj, slab 2 -> Vt transposed epilogue
// with the 32-block kv PERMUTATION (attn V-frags contiguous b128 reads).
// BK=32, 32 KB LDS -> 3 blocks/CU; double-buffer stage-before-compute.
// ---------------------------------------------------------------------------
__global__ __launch_bounds__(256)
void qkv_gemm(const bf16* __restrict__ Xcat, const bf16* __restrict__ Wqkv,
              bf16* __restrict__ Cq, bf16* __restrict__ Ck, bf16* __restrict__ Vt,
              float qscale)
{
    __shared__ bf16 Al[2][128 * 32];
    __shared__ bf16 Bl[2][128 * 32];
    const int slab  = blockIdx.x >> 5;
    const int mbase = (blockIdx.x & 31) * 128;
    const int nbase = blockIdx.y * 128;
    const int tid = threadIdx.x;
    const int w = tid >> 6, lane = tid & 63;
    const int lm = lane & 15, q4 = lane >> 4;
    const int wr = (w >> 1) * 64, wc = (w & 1) * 64;
    const int lrow = lane >> 2;                          // 16 rows / wave-chunk
    const int lsw  = ((lane & 3) ^ ((lane >> 3) & 3)) * 8;  // src col swizzle

    const bf16* A  = Xcat + (size_t)slab * 4096 * 1024;
    const bf16* Bt = Wqkv + (size_t)slab * 1024 * 1024;

    f32x4 acc[4][4] = {};

    auto stage = [&](int k0, int d) {
        #pragma unroll
        for (int i = 0; i < 2; i++) {
            int c = w * 2 + i;                           // 8 chunks of 16 rows
            gl2lds16(&A [(size_t)(mbase + c * 16 + lrow) * 1024 + k0 + lsw], &Al[d][c * 512]);
            gl2lds16(&Bt[(size_t)(nbase + c * 16 + lrow) * 1024 + k0 + lsw], &Bl[d][c * 512]);
        }
    };

    stage(0, 0);

    for (int t = 0; t < 32; t++) {
        __syncthreads();                      // buf[t&1] ready (loads had a full
        if (t < 31) stage((t + 1) * 32, (t + 1) & 1);   // compute phase to land)
        const bf16* Ad = &Al[t & 1][0];
        const bf16* Bd = &Bl[t & 1][0];
        __builtin_amdgcn_s_setprio(1);
        {
            bf16x8 a[4], bfr[4];
            const int g = (q4 ^ ((lm >> 1) & 3)) * 8;    // matches staging swz
            #pragma unroll
            for (int i = 0; i < 4; i++) a[i]   = *(const bf16x8*)&Ad[(wr + i * 16 + lm) * 32 + g];
            #pragma unroll
            for (int j = 0; j < 4; j++) bfr[j] = *(const bf16x8*)&Bd[(wc + j * 16 + lm) * 32 + g];
            #pragma unroll
            for (int i = 0; i < 4; i++)
                #pragma unroll
                for (int j = 0; j < 4; j++)
                    acc[i][j] = MFMA16(a[i], bfr[j], acc[i][j]);
        }
        __builtin_amdgcn_s_setprio(0);
    }

    if (slab == 2) {
        #pragma unroll
        for (int i = 0; i < 4; i++)
            #pragma unroll
            for (int j = 0; j < 4; j++) {
                int s0  = mbase + wr + i * 16 + q4 * 4;      // kv, multiple of 4
                int col = nbase + wc + j * 16 + lm;          // e
                int sp  = (s0 & ~31) | (((s0 >> 2) & 3) * 8) | (((s0 >> 4) & 1) * 4);
                bf16x4 p = { (bf16)acc[i][j][0], (bf16)acc[i][j][1],
                             (bf16)acc[i][j][2], (bf16)acc[i][j][3] };
                *(bf16x4*)&Vt[(size_t)col * 4096 + sp] = p;
            }
    } else {
        bf16* C = (slab == 0) ? Cq : Ck;
        const float scale = (slab == 0) ? qscale : 1.0f;
        #pragma unroll
        for (int i = 0; i < 4; i++)
            #pragma unroll
            for (int j = 0; j < 4; j++)
                #pragma unroll
                for (int r = 0; r < 4; r++) {
                    int row = mbase + wr + i * 16 + q4 * 4 + r;
                    int col = nbase + wc + j * 16 + lm;
                    C[(size_t)row * 1024 + col] = (bf16)(acc[i][j][r] * scale);
                }
    }
}

// ---------------------------------------------------------------------------
// Output projection, 64x128 (MxN) tiles, grid (64, 8) = 2 blocks/CU.
// out[4096,1024] fp32 = Hd bf16 @ Wot^T. Double-buffered schedule.
// ---------------------------------------------------------------------------
__global__ __launch_bounds__(256)
void outproj_gemm(const bf16* __restrict__ A, const bf16* __restrict__ Bt,
                  float* __restrict__ C)
{
    __shared__ bf16 Al[2][64 * 64];
    __shared__ bf16 Bl[2][128 * 64];
    const int mbase = blockIdx.x * 64;
    const int nbase = blockIdx.y * 128;
    const int tid = threadIdx.x;
    const int w = tid >> 6, lane = tid & 63;
    const int lm = lane & 15, q4 = lane >> 4;
    const int wm = (w >> 1) * 32, wn = (w & 1) * 64;   // 32x64 per wave
    const int lrow = lane >> 3, lsw = ((lane & 7) ^ lrow) * 8;

    f32x4 acc[2][4] = {};

    auto stage = [&](int k0, int d) {
        #pragma unroll
        for (int i = 0; i < 2; i++) {
            int c = w * 2 + i;                          // 8 chunks of 8 rows
            gl2lds16(&A[(size_t)(mbase + c * 8 + lrow) * 1024 + k0 + lsw], &Al[d][c * 512]);
        }
        #pragma unroll
        for (int i = 0; i < 4; i++) {
            int c = w * 4 + i;                          // 16 chunks of 8 rows
            gl2lds16(&Bt[(size_t)(nbase + c * 8 + lrow) * 1024 + k0 + lsw], &Bl[d][c * 512]);
        }
    };

    stage(0, 0);

    for (int t = 0; t < 16; t++) {
        __syncthreads();
        if (t < 15) stage((t + 1) * 64, (t + 1) & 1);
        const bf16* Ad = &Al[t & 1][0];
        const bf16* Bd = &Bl[t & 1][0];
        __builtin_amdgcn_s_setprio(1);
        #pragma unroll
        for (int kk2 = 0; kk2 < 2; kk2++) {
            bf16x8 a[2], bfr[4];
            const int g = ((kk2 * 4 + q4) ^ (lm & 7)) * 8;
            #pragma unroll
            for (int i = 0; i < 2; i++) a[i]   = *(const bf16x8*)&Ad[(wm + i * 16 + lm) * 64 + g];
            #pragma unroll
            for (int j = 0; j < 4; j++) bfr[j] = *(const bf16x8*)&Bd[(wn + j * 16 + lm) * 64 + g];
            #pragma unroll
            for (int i = 0; i < 2; i++)
                #pragma unroll
                for (int j = 0; j < 4; j++)
                    acc[i][j] = MFMA16(a[i], bfr[j], acc[i][j]);
        }
        __builtin_amdgcn_s_setprio(0);
    }

    #pragma unroll
    for (int i = 0; i < 2; i++)
        #pragma unroll
        for (int j = 0; j < 4; j++)
            #pragma unroll
            for (int r = 0; r < 4; r++) {
                int row = mbase + wm + i * 16 + q4 * 4 + r;
                int col = nbase + wn + j * 16 + lm;
                C[(size_t)row * 1024 + col] = acc[i][j][r];
            }
}

// ---------------------------------------------------------------------------
// Flash attention. Round-9: kv-tile 64 -> 128 per iteration (two 64-chunks
// from sub-tiled LDS Kl/Vl[2][2][64x64], 64 KB, still 2 blocks/CU).
// Rationale: r8 counters show ~40% stall with MfmaUtil+VALUBusy ~ 60%;
// the structural source is 32 barrier+vmcnt(0) drains (one per kv-64 tile)
// with only 2 barrier-locked blocks/CU to cover them. This halves the
// barrier count (16 drains amortized over 2x compute) and orders the body
// S0; S1; exp0+PV0; exp1+PV1 so S1's MFMA cluster sits before exp0's VALU
// with no dependency (intra-wave overlap; no extra LDS rotation, +32 VGPR,
// named St0/St1 = static indexing). Chunk (it,kc) == old tile 2*it+kc, so
// all 64x64 fragment/swizzle/permutation machinery is reused verbatim.
//   Kept: XCD swizzle, 64q-per-wave footprint, kv-permuted Vt, XOR LDS
//   swizzle, Lacc denom-via-MFMA, setprio, f32 LDS merge of kv-halves.
// ---------------------------------------------------------------------------
__global__ __launch_bounds__(256, 2)
void attn_kernel(const bf16* __restrict__ Qp, const bf16* __restrict__ Kp,
                 const bf16* __restrict__ Vt, bf16* __restrict__ Hd)
{
    __shared__ bf16 Kl[2][2][64 * 64];  // [dbuf][kv-chunk][64kv x 64e] 32 KB
    __shared__ bf16 Vl[2][2][64 * 64];  // [dbuf][kv-chunk][64e x 64kv] 32 KB
    __shared__ float Ls[128];           // denom merge scratch

    // XCD-aware remap (8 XCDs, 512 blocks, bijective: 512 = 8*64)
    const int n  = blockIdx.x + 16 * (blockIdx.y + 2 * blockIdx.z);
    const int m  = (n & 7) * 64 + (n >> 3);
    const int qt = m & 15, bh = m >> 4;
    const int b  = bh & 1,  h  = bh >> 1;

    const int qbase = qt * 128;
    const int tid  = threadIdx.x;
    const int w    = tid >> 6, lane = tid & 63;
    const int p    = w & 1;          // q-group: rows [p*64, p*64+64)
    const int kvh  = w >> 1;         // kv half of each 64-wide chunk
    const int lm   = lane & 15, q4 = lane >> 4;
    const int lrow = lane >> 3, lsw = ((lane & 7) ^ lrow) * 8;

    const bf16* Qh = Qp + (size_t)(b * 2048 + qbase + p * 64) * 1024 + h * 64;
    const bf16* Kh = Kp + (size_t)(b * 2048) * 1024 + h * 64;
    const bf16* Vh = Vt + (size_t)(h * 64) * 4096 + b * 2048;

    // Q fragments (loop-invariant), B-operand layout: n=lm, k=q4*8+j
    bf16x8 Qf[4][2];
    #pragma unroll
    for (int i = 0; i < 4; i++)
        #pragma unroll
        for (int kk2 = 0; kk2 < 2; kk2++)
            Qf[i][kk2] = *(const bf16x8*)&Qh[(size_t)(i * 16 + lm) * 1024 + kk2 * 32 + q4 * 8];

    const bf16 one = (bf16)1.0f;
    const bf16x8 ones = { one, one, one, one, one, one, one, one };

    f32x4 O[4][4] = {};
    f32x4 Lacc[4] = {};   // row-sums of P (softmax denom), same row layout as O

    // stage kv-128 tile kt into buffer d: K 16 row-chunks; V 2 col-halves x 8
    auto stage = [&](int kt, int d) {
        #pragma unroll
        for (int i = 0; i < 4; i++) {
            int c = w * 4 + i;                           // 16 units per block
            gl2lds16(&Kh[(size_t)(kt * 128 + c * 8 + lrow) * 1024 + lsw],
                     &Kl[d][c >> 3][(c & 7) * 512]);
            gl2lds16(&Vh[(size_t)((c & 7) * 8 + lrow) * 4096 + kt * 128 + (c >> 3) * 64 + lsw],
                     &Vl[d][c >> 3][(c & 7) * 512]);
        }
    };

    // S^T of one 64-chunk into St; wave's kv-half: ctp = kvh*2+c2
    auto Sc = [&](const bf16* Kd, f32x4 (&St)[4][2]) {
        #pragma unroll
        for (int c2 = 0; c2 < 2; c2++) {
            const int ctp = kvh * 2 + c2;
            #pragma unroll
            for (int kk2 = 0; kk2 < 2; kk2++) {
                const int g = ((kk2 * 4 + q4) ^ (lm & 7)) * 8;
                bf16x8 kf = *(const bf16x8*)&Kd[(ctp * 16 + lm) * 64 + g];
                #pragma unroll
                for (int i = 0; i < 4; i++)
                    St[i][c2] = MFMA16(kf, Qf[i][kk2], St[i][c2]);
            }
        }
    };

    // exp(St) -> Pf; Lacc += Pf*1; O += Pf*V
    auto PVc = [&](const bf16* Vd, const f32x4 (&St)[4][2]) {
        bf16x8 Pf[4];
        #pragma unroll
        for (int i = 0; i < 4; i++)
            #pragma unroll
            for (int j = 0; j < 8; j++)
                Pf[i][j] = (bf16)__builtin_amdgcn_exp2f(St[i][j >> 2][j & 3]);
        __builtin_amdgcn_s_setprio(1);
        #pragma unroll
        for (int i = 0; i < 4; i++) Lacc[i] = MFMA16(Pf[i], ones, Lacc[i]);
        const int gv = ((kvh * 4 + q4) ^ (lm & 7)) * 8;
        #pragma unroll
        for (int et = 0; et < 4; et++) {
            bf16x8 vf = *(const bf16x8*)&Vd[(et * 16 + lm) * 64 + gv];
            #pragma unroll
            for (int i = 0; i < 4; i++)
                O[i][et] = MFMA16(Pf[i], vf, O[i][et]);
        }
        __builtin_amdgcn_s_setprio(0);
    };

    stage(0, 0);

    for (int it = 0; it < 16; it++) {
        __syncthreads();                                 // buf[it&1] ready
        if (it < 15) stage(it + 1, (it + 1) & 1);        // overlap with compute
        const int d = it & 1;

        f32x4 St0[4][2] = {}, St1[4][2] = {};
        __builtin_amdgcn_s_setprio(1);
        Sc(&Kl[d][0][0], St0);                           // S chunk 0
        Sc(&Kl[d][1][0], St1);                           // S chunk 1 (indep)
        __builtin_amdgcn_s_setprio(0);
        PVc(&Vl[d][0][0], St0);                          // exp0 overlaps S1 tail
        PVc(&Vl[d][1][0], St1);
    }

    // ---- merge the two kv-halves via LDS (Ol aliases Kl: 32 KB) ----
    __syncthreads();                       // last tile's reads done
    float* Ol = (float*)&Kl[0][0][0];      // [p][64 rows][64 cols] f32
    if (kvh == 1) {
        #pragma unroll
        for (int i = 0; i < 4; i++)
            #pragma unroll
            for (int et = 0; et < 4; et++)
                #pragma unroll
                for (int r = 0; r < 4; r++)
                    Ol[(p * 64 + i * 16 + q4 * 4 + r) * 64 + et * 16 + lm] = O[i][et][r];
        if (lm == 0) {
            #pragma unroll
            for (int i = 0; i < 4; i++)
                #pragma unroll
                for (int r = 0; r < 4; r++)
                    Ls[p * 64 + i * 16 + q4 * 4 + r] = Lacc[i][r];
        }
    }
    __syncthreads();
    if (kvh == 0) {
        #pragma unroll
        for (int i = 0; i < 4; i++) {
            float rl[4];
            #pragma unroll
            for (int r = 0; r < 4; r++)
                rl[r] = 1.0f / (Lacc[i][r] + Ls[p * 64 + i * 16 + q4 * 4 + r]);
            #pragma unroll
            for (int et = 0; et < 4; et++)
                #pragma unroll
                for (int r = 0; r < 4; r++) {
                    float o = O[i][et][r] +
                              Ol[(p * 64 + i * 16 + q4 * 4 + r) * 64 + et * 16 + lm];
                    int row = b * 2048 + qbase + p * 64 + i * 16 + q4 * 4 + r;
                    Hd[(size_t)row * 1024 + h * 64 + et * 16 + lm] = (bf16)(o * rl[r]);
                }
        }
    }
}

extern "C" void kernel_launch(void* const* d_in, const int* in_sizes, int n_in,
                              void* d_out, int out_size, void* d_ws, size_t ws_size,
                              hipStream_t stream)
{
    const float* q  = (const float*)d_in[0];
    const float* k  = (const float*)d_in[1];
    const float* v  = (const float*)d_in[2];
    const float* Wq = (const float*)d_in[3];
    const float* Wk = (const float*)d_in[4];
    const float* Wv = (const float*)d_in[5];
    const float* Wo = (const float*)d_in[6];
    float* out = (float*)d_out;

    // ws (bf16 elems, Mi = 1024*1024; 24Mi = 48 MB):
    //  [ 0, 4) qb -> Hd (attn out; qb dead after qkv_gemm)   [ 4, 8) kb
    //  [ 8,12) vb    [12,15) Wqkv   [15,16) Wot   [16,20) Qproj   [20,24) Kproj
    // Vt (bf16, 8 MB, kv-permuted) lives in d_out (16 MB fp32), overwritten
    // by outproj at the very end.
    const size_t Mi = 1024 * 1024;
    bf16* Xcat  = (bf16*)d_ws;
    bf16* Hd    = Xcat;                   // alias qb
    bf16* Wqkv  = Xcat + 12 * Mi;
    bf16* Wot   = Xcat + 15 * Mi;
    bf16* Qproj = Xcat + 16 * Mi;
    bf16* Kproj = Xcat + 20 * Mi;
    bf16* Vtb   = (bf16*)d_out;

    const float qscale = 0.125f * 1.4426950408889634f;  // 1/sqrt(64) * log2(e)

    prep_kernel<<<7168, 256, 0, stream>>>(q, k, v, Wq, Wk, Wv, Wo, Xcat, Wqkv, Wot);
    qkv_gemm<<<dim3(96, 8), 256, 0, stream>>>(Xcat, Wqkv, Qproj, Kproj, Vtb, qscale);
    attn_kernel<<<dim3(16, 2, 16), 256, 0, stream>>>(Qproj, Kproj, Vtb, Hd);
    outproj_gemm<<<dim3(64, 8), 256, 0, stream>>>(Hd, Wot, out);
}